// Round 1
// baseline (91.662 us; speedup 1.0000x reference)
//
#include <hip/hip_runtime.h>

// LIF recurrence: mem = 0.9*mem + x; spike = (mem >= 1); record spike & mem;
// mem -= spike. T=20 steps.
//
// Output layout (concatenated flat, return order):
//   out[0          .. T*N-1]   = spike_trains  [T][64][8192]
//   out[T*N        .. 2*T*N-1] = membrane_pot  [T][64][8192]
//
// R3 change: time-split redundant recompute for occupancy.
//   Previous version: 1 thread per float4 for all 20 steps -> 512 blocks ->
//   2 waves/SIMD. Store stream ran at ~2.5 TB/s while the harness's own fill
//   kernel hits 6.05 TB/s on the same buffer -> we were occupancy/issue
//   limited, not HBM limited.
//   Now: grid.y = 4 time-groups of 5 steps. Each thread replays the
//   recurrence from t=0 (compute is ~2 VALU ops/step, free vs the 84 MB
//   store stream) and stores only its own 5 steps. 2048 blocks -> 32
//   waves/CU (full occupancy), 10 NT stores per thread.
//   Replay is bit-identical: same op sequence with forced mul-then-add
//   rounding (__fmul_rn/__fadd_rn), no FMA contraction -> absmax stays 0.

#define TSTEPS 20
#define GROUPS 4
#define SPG (TSTEPS / GROUPS)   // 5 stored steps per thread

typedef float v4f __attribute__((ext_vector_type(4)));

__global__ __launch_bounds__(256) void
TemporalEncoding_57672820850797_kernel(const v4f* __restrict__ x,
                                       float* __restrict__ out, int n4) {
    int i = blockIdx.x * blockDim.x + threadIdx.x;  // float4 index
    if (i >= n4) return;
    const int tstart = blockIdx.y * SPG;            // uniform per block

    const v4f xv = x[i];  // 2 MB input; re-read by 4 groups -> L2 hit

    float m0 = 0.f, m1 = 0.f, m2 = 0.f, m3 = 0.f;

    // One recurrence step: mem = 0.9*mem + x (separate rounding, no FMA),
    // spike = mem >= 1.0 (computed BEFORE reset), then mem -= spike.
#define LIF_STEP(S0, S1, S2, S3)                       \
    m0 = __fadd_rn(__fmul_rn(0.9f, m0), xv.x);         \
    m1 = __fadd_rn(__fmul_rn(0.9f, m1), xv.y);         \
    m2 = __fadd_rn(__fmul_rn(0.9f, m2), xv.z);         \
    m3 = __fadd_rn(__fmul_rn(0.9f, m3), xv.w);         \
    S0 = (m0 >= 1.0f) ? 1.0f : 0.0f;                   \
    S1 = (m1 >= 1.0f) ? 1.0f : 0.0f;                   \
    S2 = (m2 >= 1.0f) ? 1.0f : 0.0f;                   \
    S3 = (m3 >= 1.0f) ? 1.0f : 0.0f;

    // Warm-up replay: t in [0, tstart), no stores. Trip count is
    // block-uniform (0/5/10/15) -> no divergence; ~4 VALU ops per step.
    for (int t = 0; t < tstart; ++t) {
        float s0, s1, s2, s3;
        LIF_STEP(s0, s1, s2, s3)
        m0 -= s0;
        m1 -= s1;
        m2 -= s2;
        m3 -= s3;
    }

    // Stored steps: t in [tstart, tstart + SPG)
    v4f* __restrict__ spikes =
        reinterpret_cast<v4f*>(out) + (size_t)tstart * n4 + i;
    v4f* __restrict__ mems = spikes + (size_t)TSTEPS * n4;

#pragma unroll
    for (int k = 0; k < SPG; ++k) {
        float s0, s1, s2, s3;
        LIF_STEP(s0, s1, s2, s3)

        v4f sv; sv.x = s0; sv.y = s1; sv.z = s2; sv.w = s3;
        v4f mv; mv.x = m0; mv.y = m1; mv.z = m2; mv.w = m3;
        __builtin_nontemporal_store(sv, spikes);
        __builtin_nontemporal_store(mv, mems);
        spikes += n4;
        mems   += n4;

        m0 -= s0;
        m1 -= s1;
        m2 -= s2;
        m3 -= s3;
    }
#undef LIF_STEP
}

extern "C" void kernel_launch(void* const* d_in, const int* in_sizes, int n_in,
                              void* d_out, int out_size, void* d_ws, size_t ws_size,
                              hipStream_t stream) {
    const float* x = (const float*)d_in[0];
    float* out = (float*)d_out;
    const int n = in_sizes[0];       // 64*8192 = 524288
    const int n4 = n / 4;            // 131072 float4 lanes
    const int block = 256;
    dim3 grid((n4 + block - 1) / block, GROUPS);  // 512 x 4 = 2048 blocks
    TemporalEncoding_57672820850797_kernel<<<grid, block, 0, stream>>>(
        (const v4f*)x, out, n4);
}

// Round 2
// 87.786 us; speedup vs baseline: 1.0442x; 1.0442x over previous
//
#include <hip/hip_runtime.h>

// LIF recurrence: mem = 0.9*mem + x; spike = (mem >= 1); record spike & mem;
// mem -= spike. T=20 steps, elementwise-independent -> one thread per float4.
//
// Output layout (concatenated flat, return order):
//   out[0          .. T*N-1]   = spike_trains  [T][64][8192]
//   out[T*N        .. 2*T*N-1] = membrane_pot  [T][64][8192]
//
// R4 change: REVERT R3's time-split recompute (neutral perf, broke bit-
// exactness: absmax 0 -> 0.0078125) and REVERT R2's non-temporal stores.
// Evidence: R3 quadrupled occupancy with zero time delta -> not latency-
// bound; kernel sustains ~2.4 TB/s on the 84 MB write stream while the
// harness's fillBufferAligned hits 6.05 TB/s on the SAME buffer with plain
// stores. Theory: NT stores bypass L2 write-allocate, so each store costs a
// full HBM round-trip against the small per-CU store queue; plain stores
// complete into the 32 MB L2 and drain at full write-back BW.
//
// Numerics: forced mul-then-add rounding (__fmul_rn/__fadd_rn) to match
// numpy fp32 exactly -- FMA contraction can flip the >=1.0 threshold by
// 1 ulp. This exact sequence measured absmax=0.0 in R2.

#define TSTEPS 20

typedef float v4f __attribute__((ext_vector_type(4)));

__global__ __launch_bounds__(256) void
TemporalEncoding_57672820850797_kernel(const v4f* __restrict__ x,
                                       float* __restrict__ out, int n4) {
    int i = blockIdx.x * blockDim.x + threadIdx.x;  // float4 index
    if (i >= n4) return;

    const v4f xv = x[i];
    v4f* __restrict__ spikes = reinterpret_cast<v4f*>(out) + i;
    v4f* __restrict__ mems   = reinterpret_cast<v4f*>(out) + (size_t)TSTEPS * n4 + i;

    float m0 = 0.f, m1 = 0.f, m2 = 0.f, m3 = 0.f;

#pragma unroll
    for (int t = 0; t < TSTEPS; ++t) {
        // mem = 0.9*mem + x, with separate rounding steps (no FMA contraction)
        m0 = __fadd_rn(__fmul_rn(0.9f, m0), xv.x);
        m1 = __fadd_rn(__fmul_rn(0.9f, m1), xv.y);
        m2 = __fadd_rn(__fmul_rn(0.9f, m2), xv.z);
        m3 = __fadd_rn(__fmul_rn(0.9f, m3), xv.w);

        float s0 = (m0 >= 1.0f) ? 1.0f : 0.0f;
        float s1 = (m1 >= 1.0f) ? 1.0f : 0.0f;
        float s2 = (m2 >= 1.0f) ? 1.0f : 0.0f;
        float s3 = (m3 >= 1.0f) ? 1.0f : 0.0f;

        v4f sv; sv.x = s0; sv.y = s1; sv.z = s2; sv.w = s3;
        v4f mv; mv.x = m0; mv.y = m1; mv.z = m2; mv.w = m3;
        *spikes = sv;   // plain store: complete into L2, drain at WB BW
        *mems   = mv;
        spikes += n4;
        mems   += n4;

        // reset: mem -= spike*thr  (thr = 1.0, exact subtraction)
        m0 -= s0;
        m1 -= s1;
        m2 -= s2;
        m3 -= s3;
    }
}

extern "C" void kernel_launch(void* const* d_in, const int* in_sizes, int n_in,
                              void* d_out, int out_size, void* d_ws, size_t ws_size,
                              hipStream_t stream) {
    const float* x = (const float*)d_in[0];
    float* out = (float*)d_out;
    const int n = in_sizes[0];       // 64*8192 = 524288
    const int n4 = n / 4;            // 131072 float4 lanes
    const int block = 256;
    const int grid = (n4 + block - 1) / block;  // 512 blocks
    TemporalEncoding_57672820850797_kernel<<<grid, block, 0, stream>>>(
        (const v4f*)x, out, n4);
}